// Round 5
// baseline (301.858 us; speedup 1.0000x reference)
//
#include <hip/hip_runtime.h>
#include <hip/hip_cooperative_groups.h>

namespace cg = cooperative_groups;

#define N_ROWS 8192
#define DIM 256
#define EPSF 1e-8f

typedef _Float16 f16x8 __attribute__((ext_vector_type(8)));
typedef _Float16 f16x4 __attribute__((ext_vector_type(4)));
typedef float f32x4 __attribute__((ext_vector_type(4)));

// ===========================================================================
// MEGA: all phases in one cooperative kernel.  512 blocks x 256 threads
// (2 blocks/CU guaranteed: VGPR<=256 via launch_bounds, LDS 18.3 KB).
// Replaces 6 dispatches (memset + 5 kernels) whose fixed per-dispatch costs
// dominated rounds 2-4 (grid-resizing moved nothing; pipe changes did).
// ===========================================================================
__global__ __launch_bounds__(256, 2) void mega(
    const float* __restrict__ T, float* __restrict__ inv_norm,
    double* __restrict__ s_part, double* __restrict__ s,
    float* __restrict__ inv_rs, float* __restrict__ partials,
    _Float16* __restrict__ Mt, float* __restrict__ out)
{
    cg::grid_group grid = cg::this_grid();
    __shared__ double sacc[4][DIM];        // P1 / P1b scratch (8 KB)
    __shared__ _Float16 As[64][40];        // P3 / P5 tiles (5 KB each)
    __shared__ _Float16 Bs[64][40];

    const int tid = threadIdx.x;
    const int bid = blockIdx.x;
    const int lane = tid & 63;
    const int wave = tid >> 6;

    // ---- P1: inv_norm (fp32) + per-block fp64 column-sums of x_hat.
    // 16 rows/block (512*16 = 8192), wave handles 4 rows, lane owns 4 cols.
    float inv_keep[4];
    {
        double a0 = 0, a1 = 0, a2 = 0, a3 = 0;
#pragma unroll
        for (int r = 0; r < 4; ++r) {
            int row = bid * 16 + wave * 4 + r;
            float4 v = ((const float4*)(T + (size_t)row * DIM))[lane];
            float ss = v.x * v.x + v.y * v.y + v.z * v.z + v.w * v.w;
#pragma unroll
            for (int o = 32; o; o >>= 1) ss += __shfl_down(ss, o);
            ss = __shfl(ss, 0);
            float inv = 1.0f / fmaxf(sqrtf(ss), EPSF);
            inv_keep[r] = inv;
            if (lane == 0) inv_norm[row] = inv;
            a0 += (double)(v.x * inv);
            a1 += (double)(v.y * inv);
            a2 += (double)(v.z * inv);
            a3 += (double)(v.w * inv);
        }
        sacc[wave][lane * 4 + 0] = a0;
        sacc[wave][lane * 4 + 1] = a1;
        sacc[wave][lane * 4 + 2] = a2;
        sacc[wave][lane * 4 + 3] = a3;
        __syncthreads();
        double t = sacc[0][tid] + sacc[1][tid] + sacc[2][tid] + sacc[3][tid];
        s_part[(size_t)bid * DIM + tid] = t;   // full overwrite, no memset
    }
    grid.sync();

    // ---- P1b: 32 blocks reduce s_part[512][256] -> s[256].
    // thread t: col c = bid*8 + (t&7) (coalesced across 8-thread groups),
    // m = t>>3 sums 16 strided bids; LDS finish over the 32 m-values.
    if (bid < 32) {
        int c8 = tid & 7, m = tid >> 3;
        int c = bid * 8 + c8;
        double sum = 0.0;
#pragma unroll
        for (int q = 0; q < 16; ++q)
            sum += s_part[(size_t)(m + 32 * q) * DIM + c];
        ((double*)sacc)[m * 8 + c8] = sum;
        __syncthreads();
        if (tid < 8) {
            double tot = 0.0;
#pragma unroll
            for (int mm = 0; mm < 32; ++mm)
                tot += ((double*)sacc)[mm * 8 + tid];
            s[bid * 8 + tid] = tot;
        }
    }
    grid.sync();

    // ---- P2: inv_rs = 1/(inv_norm * dot(T_row, s)) in fp64 (precision-
    // critical path; rs ~6e-4 possible). Same rows as P1: inv_keep reused,
    // T rows L1/L2-hot on this CU.
    {
        const double s0 = s[lane * 4 + 0], s1 = s[lane * 4 + 1],
                     s2 = s[lane * 4 + 2], s3 = s[lane * 4 + 3];
#pragma unroll
        for (int r = 0; r < 4; ++r) {
            int row = bid * 16 + wave * 4 + r;
            float4 v = ((const float4*)(T + (size_t)row * DIM))[lane];
            double d = (double)v.x * s0 + (double)v.y * s1 +
                       (double)v.z * s2 + (double)v.w * s3;
#pragma unroll
            for (int o = 32; o; o >>= 1) d += __shfl_down(d, o);
            if (lane == 0)
                inv_rs[row] = (float)(1.0 / (d * (double)inv_keep[r]));
        }
    }
    // no grid sync: P3 does not read inv_rs (P5 does, sync before P5 exists)

    // ---- P3: M-partials via fp16 MFMA.  (kx,dy,z) = (4,4,32): 64x64 output
    // tile over a 256-row slab (8 chunks of 32).  Operands transpose-staged
    // [col][i] (stride 40 halfs: frag b128 reads and b16 writes <=2-way).
    {
        const int kx = bid & 3, dy = (bid >> 2) & 3, z = bid >> 4;
        const int k0 = kx * 64, d0 = dy * 64, i0 = z * 256;
        const int wy = wave >> 1, wx = wave & 1;
        const int lm = lane & 15, lg = lane >> 4;
        const int i = tid & 31, c8 = tid >> 5;
        f32x4 acc[2][2] = {};
        float4 rA[2], rB[2];
        float rI;

        auto stage = [&](int ic) {
            int gi = i0 + ic + i;
            rI = inv_norm[gi];
            const float* rowp = T + (size_t)gi * DIM;
#pragma unroll
            for (int j = 0; j < 2; ++j) {
                int c4 = (c8 + 8 * j) * 4;
                rA[j] = *(const float4*)(rowp + k0 + c4);
                rB[j] = *(const float4*)(rowp + d0 + c4);
            }
        };
        auto commit = [&]() {
#pragma unroll
            for (int j = 0; j < 2; ++j) {
                int c4 = (c8 + 8 * j) * 4;
                As[c4 + 0][i] = (_Float16)(rA[j].x * rI);
                As[c4 + 1][i] = (_Float16)(rA[j].y * rI);
                As[c4 + 2][i] = (_Float16)(rA[j].z * rI);
                As[c4 + 3][i] = (_Float16)(rA[j].w * rI);
                Bs[c4 + 0][i] = (_Float16)rB[j].x;
                Bs[c4 + 1][i] = (_Float16)rB[j].y;
                Bs[c4 + 2][i] = (_Float16)rB[j].z;
                Bs[c4 + 3][i] = (_Float16)rB[j].w;
            }
        };
        auto compute = [&]() {
            f16x8 af[2], bf[2];
#pragma unroll
            for (int mt = 0; mt < 2; ++mt)
                af[mt] = *(const f16x8*)&As[wy * 32 + mt * 16 + lm][lg * 8];
#pragma unroll
            for (int nt = 0; nt < 2; ++nt)
                bf[nt] = *(const f16x8*)&Bs[wx * 32 + nt * 16 + lm][lg * 8];
#pragma unroll
            for (int mt = 0; mt < 2; ++mt)
#pragma unroll
                for (int nt = 0; nt < 2; ++nt)
                    acc[mt][nt] = __builtin_amdgcn_mfma_f32_16x16x32_f16(
                        af[mt], bf[nt], acc[mt][nt], 0, 0, 0);
        };

        stage(0);
        commit();
        __syncthreads();
        for (int c = 1; c < 8; ++c) {
            stage(c * 32);
            compute();
            __syncthreads();
            commit();
            __syncthreads();
        }
        compute();

        // C/D frag: col = lane&15, row = (lane>>4)*4 + reg (m89-verified)
        float* pz = partials + (size_t)z * 65536;
#pragma unroll
        for (int mt = 0; mt < 2; ++mt) {
            int km = k0 + wy * 32 + mt * 16 + lg * 4;
#pragma unroll
            for (int nt = 0; nt < 2; ++nt) {
                int dn = d0 + wx * 32 + nt * 16 + lm;
#pragma unroll
                for (int r = 0; r < 4; ++r)
                    pz[(size_t)(km + r) * 256 + dn] = acc[mt][nt][r];
            }
        }
    }
    grid.sync();

    // ---- P4: reduce 32 partial slabs -> Mt (fp16, TRANSPOSED for P5's
    // k-contiguous B loads).  256 blocks, one output/thread, coalesced reads.
    if (bid < 256) {
        int g = bid * 256 + tid;
        int k = g >> 8, d = g & 255;
        const float* p = partials + (size_t)k * 256 + d;
        float a0 = 0.f, a1 = 0.f, a2 = 0.f, a3 = 0.f;
#pragma unroll
        for (int zz = 0; zz < 32; zz += 4) {
            a0 += p[(size_t)(zz + 0) * 65536];
            a1 += p[(size_t)(zz + 1) * 65536];
            a2 += p[(size_t)(zz + 2) * 65536];
            a3 += p[(size_t)(zz + 3) * 65536];
        }
        Mt[(size_t)d * 256 + k] = (_Float16)((a0 + a1) + (a2 + a3));
    }
    grid.sync();

    // ---- P5: out = diag(inv_rs) * Xhat * M via fp16 MFMA.  64x64 tiles,
    // (bid>>2) = i-tile 0..127, (bid&3) = d-tile 0..3.  Natural [row][k] LDS.
    {
        const int i0 = (bid >> 2) * 64;
        const int d0 = (bid & 3) * 64;
        const int wy = wave >> 1, wx = wave & 1;
        const int lm = lane & 15, lg = lane >> 4;
        f32x4 acc[2][2] = {};
        float4 rA[2];
        float rI2[2];
        f16x8 rB;
        const int db = tid >> 2, k8 = (tid & 3) * 8;

        auto stage = [&](int kc) {
#pragma unroll
            for (int j = 0; j < 2; ++j) {
                int idx = tid + 256 * j;
                int ia = idx >> 3;
                int c4 = (idx & 7) * 4;
                int gi = i0 + ia;
                rI2[j] = inv_norm[gi];
                rA[j] = *(const float4*)(T + (size_t)gi * DIM + kc + c4);
            }
            rB = *(const f16x8*)(Mt + (size_t)(d0 + db) * 256 + kc + k8);
        };
        auto commit = [&]() {
#pragma unroll
            for (int j = 0; j < 2; ++j) {
                int idx = tid + 256 * j;
                int ia = idx >> 3;
                int c4 = (idx & 7) * 4;
                float inv = rI2[j];
                f16x4 h;
                h[0] = (_Float16)(rA[j].x * inv);
                h[1] = (_Float16)(rA[j].y * inv);
                h[2] = (_Float16)(rA[j].z * inv);
                h[3] = (_Float16)(rA[j].w * inv);
                *(f16x4*)&As[ia][c4] = h;
            }
            *(f16x8*)&Bs[db][k8] = rB;
        };
        auto compute = [&]() {
            f16x8 af[2], bf[2];
#pragma unroll
            for (int ti = 0; ti < 2; ++ti)
                af[ti] = *(const f16x8*)&As[wy * 32 + ti * 16 + lm][lg * 8];
#pragma unroll
            for (int tj = 0; tj < 2; ++tj)
                bf[tj] = *(const f16x8*)&Bs[wx * 32 + tj * 16 + lm][lg * 8];
#pragma unroll
            for (int ti = 0; ti < 2; ++ti)
#pragma unroll
                for (int tj = 0; tj < 2; ++tj)
                    acc[ti][tj] = __builtin_amdgcn_mfma_f32_16x16x32_f16(
                        af[ti], bf[tj], acc[ti][tj], 0, 0, 0);
        };

        stage(0);
        commit();
        __syncthreads();
        for (int c = 1; c < 8; ++c) {
            stage(c * 32);
            compute();
            __syncthreads();
            commit();
            __syncthreads();
        }
        compute();

#pragma unroll
        for (int ti = 0; ti < 2; ++ti) {
#pragma unroll
            for (int r = 0; r < 4; ++r) {
                int gi = i0 + wy * 32 + ti * 16 + lg * 4 + r;
                float ir = inv_rs[gi];
#pragma unroll
                for (int tj = 0; tj < 2; ++tj)
                    out[(size_t)gi * DIM + d0 + wx * 32 + tj * 16 + lm] =
                        acc[ti][tj][r] * ir;
            }
        }
    }
}

// ===========================================================================
// FALLBACK path: round-4 multi-kernel pipeline (proven passing), used only
// if the cooperative launch fails (e.g. unsupported under graph capture).
// ===========================================================================
__global__ __launch_bounds__(256) void k1_norm_s(const float* __restrict__ T,
                                                 float* __restrict__ inv_norm,
                                                 double* __restrict__ s) {
    __shared__ double sacc[4][DIM];
    const int lane = threadIdx.x & 63;
    const int wave = threadIdx.x >> 6;
    const int gw = blockIdx.x * 4 + wave;
    const int nw = gridDim.x * 4;
    double a0 = 0.0, a1 = 0.0, a2 = 0.0, a3 = 0.0;
    for (int row = gw; row < N_ROWS; row += nw) {
        float4 v = ((const float4*)(T + (size_t)row * DIM))[lane];
        float ss = v.x * v.x + v.y * v.y + v.z * v.z + v.w * v.w;
#pragma unroll
        for (int o = 32; o; o >>= 1) ss += __shfl_down(ss, o);
        ss = __shfl(ss, 0);
        float inv = 1.0f / fmaxf(sqrtf(ss), EPSF);
        if (lane == 0) inv_norm[row] = inv;
        a0 += (double)(v.x * inv);
        a1 += (double)(v.y * inv);
        a2 += (double)(v.z * inv);
        a3 += (double)(v.w * inv);
    }
    sacc[wave][lane * 4 + 0] = a0;
    sacc[wave][lane * 4 + 1] = a1;
    sacc[wave][lane * 4 + 2] = a2;
    sacc[wave][lane * 4 + 3] = a3;
    __syncthreads();
    const int tid = threadIdx.x;
    double t = sacc[0][tid] + sacc[1][tid] + sacc[2][tid] + sacc[3][tid];
    atomicAdd(&s[tid], t);
}

__global__ __launch_bounds__(256) void k2_rowsum(const float* __restrict__ T,
                                                 const float* __restrict__ inv_norm,
                                                 const double* __restrict__ s,
                                                 float* __restrict__ inv_rs) {
    const int lane = threadIdx.x & 63;
    const int wave = threadIdx.x >> 6;
    const int gw = blockIdx.x * 4 + wave;
    const int nw = gridDim.x * 4;
    const double s0 = s[lane * 4 + 0];
    const double s1 = s[lane * 4 + 1];
    const double s2 = s[lane * 4 + 2];
    const double s3 = s[lane * 4 + 3];
    for (int row = gw; row < N_ROWS; row += nw) {
        float4 v = ((const float4*)(T + (size_t)row * DIM))[lane];
        double d = (double)v.x * s0 + (double)v.y * s1 + (double)v.z * s2 + (double)v.w * s3;
#pragma unroll
        for (int o = 32; o; o >>= 1) d += __shfl_down(d, o);
        if (lane == 0)
            inv_rs[row] = (float)(1.0 / (d * (double)inv_norm[row]));
    }
}

__global__ __launch_bounds__(256) void k_gemmM_mfma(const float* __restrict__ T,
                                                    const float* __restrict__ inv_norm,
                                                    float* __restrict__ partials) {
    const int k0 = blockIdx.x * 128;
    const int d0 = blockIdx.y * 128;
    const int i0 = blockIdx.z * 256;
    __shared__ _Float16 As[128][40];
    __shared__ _Float16 Bs[128][40];
    const int tid = threadIdx.x;
    const int l = tid & 63;
    const int w = tid >> 6;
    const int wy = w >> 1, wx = w & 1;
    const int lm = l & 15, lg = l >> 4;
    f32x4 acc[4][4] = {};
    float4 rA[4], rB[4];
    float rI[4];

    auto stage = [&](int ic) {
#pragma unroll
        for (int j = 0; j < 4; ++j) {
            int idx = tid + 256 * j;
            int i = idx & 31;
            int c4 = (idx >> 5) * 4;
            int gi = i0 + ic + i;
            rI[j] = inv_norm[gi];
            const float* rowp = T + (size_t)gi * DIM;
            rA[j] = *(const float4*)(rowp + k0 + c4);
            rB[j] = *(const float4*)(rowp + d0 + c4);
        }
    };
    auto commit = [&]() {
#pragma unroll
        for (int j = 0; j < 4; ++j) {
            int idx = tid + 256 * j;
            int i = idx & 31;
            int c4 = (idx >> 5) * 4;
            float inv = rI[j];
            As[c4 + 0][i] = (_Float16)(rA[j].x * inv);
            As[c4 + 1][i] = (_Float16)(rA[j].y * inv);
            As[c4 + 2][i] = (_Float16)(rA[j].z * inv);
            As[c4 + 3][i] = (_Float16)(rA[j].w * inv);
            Bs[c4 + 0][i] = (_Float16)rB[j].x;
            Bs[c4 + 1][i] = (_Float16)rB[j].y;
            Bs[c4 + 2][i] = (_Float16)rB[j].z;
            Bs[c4 + 3][i] = (_Float16)rB[j].w;
        }
    };
    auto compute = [&]() {
        f16x8 af[4], bf[4];
#pragma unroll
        for (int mt = 0; mt < 4; ++mt)
            af[mt] = *(const f16x8*)&As[wy * 64 + mt * 16 + lm][lg * 8];
#pragma unroll
        for (int nt = 0; nt < 4; ++nt)
            bf[nt] = *(const f16x8*)&Bs[wx * 64 + nt * 16 + lm][lg * 8];
#pragma unroll
        for (int mt = 0; mt < 4; ++mt)
#pragma unroll
            for (int nt = 0; nt < 4; ++nt)
                acc[mt][nt] = __builtin_amdgcn_mfma_f32_16x16x32_f16(
                    af[mt], bf[nt], acc[mt][nt], 0, 0, 0);
    };

    stage(0);
    commit();
    __syncthreads();
    for (int c = 1; c < 8; ++c) {
        stage(c * 32);
        compute();
        __syncthreads();
        commit();
        __syncthreads();
    }
    compute();

    float* pz = partials + (size_t)blockIdx.z * 65536;
#pragma unroll
    for (int mt = 0; mt < 4; ++mt) {
        int km = k0 + wy * 64 + mt * 16 + lg * 4;
#pragma unroll
        for (int nt = 0; nt < 4; ++nt) {
            int dn = d0 + wx * 64 + nt * 16 + lm;
#pragma unroll
            for (int r = 0; r < 4; ++r)
                pz[(size_t)(km + r) * 256 + dn] = acc[mt][nt][r];
        }
    }
}

__global__ __launch_bounds__(256) void k_reduceM(const float* __restrict__ partials,
                                                 _Float16* __restrict__ Mt) {
    const int g = blockIdx.x * 256 + threadIdx.x;
    const int k = g >> 8, d = g & 255;
    const float* p = partials + (size_t)k * 256 + d;
    float a0 = 0.f, a1 = 0.f, a2 = 0.f, a3 = 0.f;
#pragma unroll
    for (int z = 0; z < 32; z += 4) {
        a0 += p[(size_t)(z + 0) * 65536];
        a1 += p[(size_t)(z + 1) * 65536];
        a2 += p[(size_t)(z + 2) * 65536];
        a3 += p[(size_t)(z + 3) * 65536];
    }
    Mt[(size_t)d * 256 + k] = (_Float16)((a0 + a1) + (a2 + a3));
}

__global__ __launch_bounds__(256) void k3_mfma(const float* __restrict__ T,
                                               const float* __restrict__ inv_norm,
                                               const _Float16* __restrict__ Mt,
                                               const float* __restrict__ inv_rs,
                                               float* __restrict__ out) {
    const int i0 = blockIdx.x * 64;
    const int d0 = blockIdx.y * 64;
    __shared__ _Float16 As[64][40];
    __shared__ _Float16 Bs[64][40];
    const int tid = threadIdx.x;
    const int l = tid & 63;
    const int w = tid >> 6;
    const int wy = w >> 1, wx = w & 1;
    const int lm = l & 15, lg = l >> 4;
    f32x4 acc[2][2] = {};
    float4 rA[2];
    float rI[2];
    f16x8 rB;
    const int db = tid >> 2, k8 = (tid & 3) * 8;

    auto stage = [&](int kc) {
#pragma unroll
        for (int j = 0; j < 2; ++j) {
            int idx = tid + 256 * j;
            int ia = idx >> 3;
            int c4 = (idx & 7) * 4;
            int gi = i0 + ia;
            rI[j] = inv_norm[gi];
            rA[j] = *(const float4*)(T + (size_t)gi * DIM + kc + c4);
        }
        rB = *(const f16x8*)(Mt + (size_t)(d0 + db) * 256 + kc + k8);
    };
    auto commit = [&]() {
#pragma unroll
        for (int j = 0; j < 2; ++j) {
            int idx = tid + 256 * j;
            int ia = idx >> 3;
            int c4 = (idx & 7) * 4;
            float inv = rI[j];
            f16x4 h;
            h[0] = (_Float16)(rA[j].x * inv);
            h[1] = (_Float16)(rA[j].y * inv);
            h[2] = (_Float16)(rA[j].z * inv);
            h[3] = (_Float16)(rA[j].w * inv);
            *(f16x4*)&As[ia][c4] = h;
        }
        *(f16x8*)&Bs[db][k8] = rB;
    };
    auto compute = [&]() {
        f16x8 af[2], bf[2];
#pragma unroll
        for (int ti = 0; ti < 2; ++ti)
            af[ti] = *(const f16x8*)&As[wy * 32 + ti * 16 + lm][lg * 8];
#pragma unroll
        for (int tj = 0; tj < 2; ++tj)
            bf[tj] = *(const f16x8*)&Bs[wx * 32 + tj * 16 + lm][lg * 8];
#pragma unroll
        for (int ti = 0; ti < 2; ++ti)
#pragma unroll
            for (int tj = 0; tj < 2; ++tj)
                acc[ti][tj] = __builtin_amdgcn_mfma_f32_16x16x32_f16(
                    af[ti], bf[tj], acc[ti][tj], 0, 0, 0);
    };

    stage(0);
    commit();
    __syncthreads();
    for (int c = 1; c < 8; ++c) {
        stage(c * 32);
        compute();
        __syncthreads();
        commit();
        __syncthreads();
    }
    compute();

#pragma unroll
    for (int ti = 0; ti < 2; ++ti) {
#pragma unroll
        for (int r = 0; r < 4; ++r) {
            int gi = i0 + wy * 32 + ti * 16 + lg * 4 + r;
            float ir = inv_rs[gi];
#pragma unroll
            for (int tj = 0; tj < 2; ++tj)
                out[(size_t)gi * DIM + d0 + wx * 32 + tj * 16 + lm] =
                    acc[ti][tj][r] * ir;
        }
    }
}

// ---------------------------------------------------------------------------
extern "C" void kernel_launch(void* const* d_in, const int* in_sizes, int n_in,
                              void* d_out, int out_size, void* d_ws, size_t ws_size,
                              hipStream_t stream) {
    const float* T = (const float*)d_in[0];
    float* out = (float*)d_out;

    // workspace layout (all 16B-aligned, ~9.2 MB of the 256 MiB ws):
    //   [0,        32768)     inv_norm  float[8192]
    //   [32768,    1081344)   s_part    double[512][256]   (mega only)
    //   [1081344,  1083392)   s         double[256]
    //   [1083392,  1116160)   inv_rs    float[8192]
    //   [1116160,  1247232)   Mt        _Float16[256*256]  (M transposed)
    //   [1247232,  +8 MiB)    partials  float[32*65536]
    char* ws = (char*)d_ws;
    float* inv_norm = (float*)(ws);
    double* s_part = (double*)(ws + 32768);
    double* s = (double*)(ws + 1081344);
    float* inv_rs = (float*)(ws + 1083392);
    _Float16* Mt = (_Float16*)(ws + 1116160);
    float* partials = (float*)(ws + 1247232);

    void* args[] = {(void*)&T, (void*)&inv_norm, (void*)&s_part, (void*)&s,
                    (void*)&inv_rs, (void*)&partials, (void*)&Mt, (void*)&out};
    hipError_t e = hipLaunchCooperativeKernel((const void*)mega, dim3(512),
                                              dim3(256), args, 0, stream);
    if (e != hipSuccess) {
        // fallback: round-4 proven multi-kernel path
        hipMemsetAsync(s, 0, 256 * sizeof(double), stream);
        k1_norm_s<<<256, 256, 0, stream>>>(T, inv_norm, s);
        k2_rowsum<<<256, 256, 0, stream>>>(T, inv_norm, s, inv_rs);
        k_gemmM_mfma<<<dim3(2, 2, 32), 256, 0, stream>>>(T, inv_norm, partials);
        k_reduceM<<<256, 256, 0, stream>>>(partials, Mt);
        k3_mfma<<<dim3(128, 4), 256, 0, stream>>>(T, inv_norm, Mt, inv_rs, out);
    }
}

// Round 8
// 111.926 us; speedup vs baseline: 2.6969x; 2.6969x over previous
//
#include <hip/hip_runtime.h>

#define N_ROWS 8192
#define DIM 256
#define EPSF 1e-8f

typedef _Float16 f16x8 __attribute__((ext_vector_type(8)));
typedef float f32x4 __attribute__((ext_vector_type(4)));

// ---------------------------------------------------------------------------
// D1: inv_norm (fp32) + deterministic per-block fp64 column-sums of x_hat.
// 512 blocks x 16 rows. No atomics, no memset needed (s_part fully written).
// ---------------------------------------------------------------------------
__global__ __launch_bounds__(256) void k1_norm(const float* __restrict__ T,
                                               float* __restrict__ inv_norm,
                                               double* __restrict__ s_part) {
    __shared__ double sacc[4][DIM];
    const int tid = threadIdx.x, bid = blockIdx.x;
    const int lane = tid & 63, wave = tid >> 6;
    double a0 = 0, a1 = 0, a2 = 0, a3 = 0;
#pragma unroll
    for (int r = 0; r < 4; ++r) {
        int row = bid * 16 + wave * 4 + r;
        float4 v = ((const float4*)(T + (size_t)row * DIM))[lane];
        float ss = v.x * v.x + v.y * v.y + v.z * v.z + v.w * v.w;
#pragma unroll
        for (int o = 32; o; o >>= 1) ss += __shfl_down(ss, o);
        ss = __shfl(ss, 0);
        float inv = 1.0f / fmaxf(sqrtf(ss), EPSF);
        if (lane == 0) inv_norm[row] = inv;
        a0 += (double)(v.x * inv);
        a1 += (double)(v.y * inv);
        a2 += (double)(v.z * inv);
        a3 += (double)(v.w * inv);
    }
    sacc[wave][lane * 4 + 0] = a0;
    sacc[wave][lane * 4 + 1] = a1;
    sacc[wave][lane * 4 + 2] = a2;
    sacc[wave][lane * 4 + 3] = a3;
    __syncthreads();
    double t = sacc[0][tid] + sacc[1][tid] + sacc[2][tid] + sacc[3][tid];
    s_part[(size_t)bid * DIM + tid] = t;
}

// ---------------------------------------------------------------------------
// D2 (fused): block-role split.
//   blocks 0..63   : reduce s from s_part, then inv_rs (fp64 row-dots —
//                    precision-critical; rs can be ~6e-4 from cancellation).
//   blocks 64..575 : M-partials via fp16 MFMA, 64x64 tile, 256-row K-slab,
//                    double-buffered LDS (ONE barrier per 32-row chunk).
// Roles are independent (both need only k1 outputs) -> legal same-dispatch.
// ---------------------------------------------------------------------------
__global__ __launch_bounds__(256) void k2_gemmM(const float* __restrict__ T,
                                                const float* __restrict__ inv_norm,
                                                const double* __restrict__ s_part,
                                                float* __restrict__ inv_rs,
                                                float* __restrict__ partials) {
    __shared__ _Float16 As[2][64][40];   // [buf][col][i]  10.2 KB
    __shared__ _Float16 Bs[2][64][40];   //                10.2 KB
    __shared__ double sred[4][DIM];      // k2 role         8.0 KB
    const int tid = threadIdx.x, bid = blockIdx.x;
    const int lane = tid & 63, wave = tid >> 6;

    if (bid < 64) {
        // ---- k2 role: s = sum(s_part).  Each wave sums its 128-block range
        // for ALL 256 columns (4 cols/lane) — every sred[w][c] is written.
        // (Round-6 bug: sred[wave][tid] left 3/4 of sred uninitialized.)
        double a0 = 0, a1 = 0, a2 = 0, a3 = 0;
        for (int b = wave * 128; b < wave * 128 + 128; ++b) {
            const double* rp = s_part + (size_t)b * DIM;
            a0 += rp[lane * 4 + 0];
            a1 += rp[lane * 4 + 1];
            a2 += rp[lane * 4 + 2];
            a3 += rp[lane * 4 + 3];
        }
        sred[wave][lane * 4 + 0] = a0;
        sred[wave][lane * 4 + 1] = a1;
        sred[wave][lane * 4 + 2] = a2;
        sred[wave][lane * 4 + 3] = a3;
        __syncthreads();
        double sc = sred[0][tid] + sred[1][tid] + sred[2][tid] + sred[3][tid];
        __syncthreads();
        sred[0][tid] = sc;
        __syncthreads();
        const double s0 = sred[0][lane * 4 + 0];
        const double s1 = sred[0][lane * 4 + 1];
        const double s2 = sred[0][lane * 4 + 2];
        const double s3 = sred[0][lane * 4 + 3];
        const int slot = bid * 4 + wave;          // 0..255
        for (int k = 0; k < 32; ++k) {
            int row = slot + 256 * k;
            float4 v = ((const float4*)(T + (size_t)row * DIM))[lane];
            double d = (double)v.x * s0 + (double)v.y * s1 +
                       (double)v.z * s2 + (double)v.w * s3;
#pragma unroll
            for (int o = 32; o; o >>= 1) d += __shfl_down(d, o);
            if (lane == 0)
                inv_rs[row] = (float)(1.0 / (d * (double)inv_norm[row]));
        }
        return;
    }

    // ---- gemm role: M-partials.  g in [0,512): (kx,dy,z) = (4,4,32)
    const int g = bid - 64;
    const int k0 = (g & 3) * 64;
    const int d0 = ((g >> 2) & 3) * 64;
    const int i0 = (g >> 4) * 256;
    const int wy = wave >> 1, wx = wave & 1;      // 2x2 waves -> 32x32 each
    const int lm = lane & 15, lg = lane >> 4;
    const int i = tid & 31, c8 = (tid >> 5) * 8;  // stage map: row i, 8 cols
    f32x4 acc[2][2] = {};
    float4 rA[2], rB[2];
    float rI;

    auto stage = [&](int ic) {
        int gi = i0 + ic + i;
        rI = inv_norm[gi];
        const float* rowp = T + (size_t)gi * DIM;
        rA[0] = *(const float4*)(rowp + k0 + c8);
        rA[1] = *(const float4*)(rowp + k0 + c8 + 4);
        rB[0] = *(const float4*)(rowp + d0 + c8);
        rB[1] = *(const float4*)(rowp + d0 + c8 + 4);
    };
    auto commit = [&](int buf) {
#pragma unroll
        for (int j = 0; j < 2; ++j) {
            float4 a = rA[j], b = rB[j];
            int c = c8 + j * 4;
            As[buf][c + 0][i] = (_Float16)(a.x * rI);
            As[buf][c + 1][i] = (_Float16)(a.y * rI);
            As[buf][c + 2][i] = (_Float16)(a.z * rI);
            As[buf][c + 3][i] = (_Float16)(a.w * rI);
            Bs[buf][c + 0][i] = (_Float16)b.x;
            Bs[buf][c + 1][i] = (_Float16)b.y;
            Bs[buf][c + 2][i] = (_Float16)b.z;
            Bs[buf][c + 3][i] = (_Float16)b.w;
        }
    };
    auto compute = [&](int buf) {
        f16x8 af[2], bf[2];
#pragma unroll
        for (int mt = 0; mt < 2; ++mt)
            af[mt] = *(const f16x8*)&As[buf][wy * 32 + mt * 16 + lm][lg * 8];
#pragma unroll
        for (int nt = 0; nt < 2; ++nt)
            bf[nt] = *(const f16x8*)&Bs[buf][wx * 32 + nt * 16 + lm][lg * 8];
#pragma unroll
        for (int mt = 0; mt < 2; ++mt)
#pragma unroll
            for (int nt = 0; nt < 2; ++nt)
                acc[mt][nt] = __builtin_amdgcn_mfma_f32_16x16x32_f16(
                    af[mt], bf[nt], acc[mt][nt], 0, 0, 0);
    };

    stage(0);
    commit(0);
    __syncthreads();
    for (int c = 1; c < 8; ++c) {
        stage(c * 32);            // global loads for chunk c in flight
        compute((c - 1) & 1);     // MFMA on previous chunk
        commit(c & 1);            // write other buffer (no reader conflict)
        __syncthreads();          // ONE barrier per chunk
    }
    compute(1);

    // C/D frag: col = lane&15, row = (lane>>4)*4 + reg (mega-verified r5)
    float* pz = partials + (size_t)(g >> 4) * 65536;
#pragma unroll
    for (int mt = 0; mt < 2; ++mt) {
        int km = k0 + wy * 32 + mt * 16 + lg * 4;
#pragma unroll
        for (int nt = 0; nt < 2; ++nt) {
            int dn = d0 + wx * 32 + nt * 16 + lm;
#pragma unroll
            for (int r = 0; r < 4; ++r)
                pz[(size_t)(km + r) * 256 + dn] = acc[mt][nt][r];
        }
    }
}

// ---------------------------------------------------------------------------
// D3: reduce 32 partial slabs -> Mt (fp16, TRANSPOSED for k3's k-contiguous
// B loads).  Coalesced reads, 128 KB of writes.
// ---------------------------------------------------------------------------
__global__ __launch_bounds__(256) void k_reduceM(const float* __restrict__ partials,
                                                 _Float16* __restrict__ Mt) {
    const int gidx = blockIdx.x * 256 + threadIdx.x;
    const int k = gidx >> 8, d = gidx & 255;
    const float* p = partials + (size_t)k * 256 + d;
    float a0 = 0.f, a1 = 0.f, a2 = 0.f, a3 = 0.f;
#pragma unroll
    for (int z = 0; z < 32; z += 4) {
        a0 += p[(size_t)(z + 0) * 65536];
        a1 += p[(size_t)(z + 1) * 65536];
        a2 += p[(size_t)(z + 2) * 65536];
        a3 += p[(size_t)(z + 3) * 65536];
    }
    Mt[(size_t)d * 256 + k] = (_Float16)((a0 + a1) + (a2 + a3));
}

// ---------------------------------------------------------------------------
// D4: out = diag(inv_rs) * Xhat * M via fp16 MFMA.  32x64 tiles -> 1024
// blocks (4 blocks/CU), double-buffered LDS, one barrier per chunk.
// ---------------------------------------------------------------------------
__global__ __launch_bounds__(256) void k3_mfma(const float* __restrict__ T,
                                               const float* __restrict__ inv_norm,
                                               const _Float16* __restrict__ Mt,
                                               const float* __restrict__ inv_rs,
                                               float* __restrict__ out) {
    __shared__ _Float16 As[2][32][40];   // [buf][i][k]   5.1 KB
    __shared__ _Float16 Bs[2][64][40];   // [buf][d][k]  10.2 KB
    const int tid = threadIdx.x, bid = blockIdx.x;
    const int lane = tid & 63, wave = tid >> 6;
    const int i0 = (bid >> 2) * 32;
    const int d0 = (bid & 3) * 64;
    const int wy = wave >> 1, wx = wave & 1;     // wave tile 16 x 32
    const int lm = lane & 15, lg = lane >> 4;
    f32x4 acc[2] = {};
    float4 rA;
    float rI;
    f16x8 rB;
    const int ia = tid >> 3, c4 = (tid & 7) * 4;   // A: row ia, 4 k-cols
    const int db = tid >> 2, k8 = (tid & 3) * 8;   // B: row db, 8 k-cols

    auto stage = [&](int kc) {
        rI = inv_norm[i0 + ia];
        rA = *(const float4*)(T + (size_t)(i0 + ia) * DIM + kc + c4);
        rB = *(const f16x8*)(Mt + (size_t)(d0 + db) * 256 + kc + k8);
    };
    auto commit = [&](int buf) {
        As[buf][ia][c4 + 0] = (_Float16)(rA.x * rI);
        As[buf][ia][c4 + 1] = (_Float16)(rA.y * rI);
        As[buf][ia][c4 + 2] = (_Float16)(rA.z * rI);
        As[buf][ia][c4 + 3] = (_Float16)(rA.w * rI);
        *(f16x8*)&Bs[buf][db][k8] = rB;
    };
    auto compute = [&](int buf) {
        f16x8 af = *(const f16x8*)&As[buf][wy * 16 + lm][lg * 8];
        f16x8 bf0 = *(const f16x8*)&Bs[buf][wx * 32 + lm][lg * 8];
        f16x8 bf1 = *(const f16x8*)&Bs[buf][wx * 32 + 16 + lm][lg * 8];
        acc[0] = __builtin_amdgcn_mfma_f32_16x16x32_f16(af, bf0, acc[0], 0, 0, 0);
        acc[1] = __builtin_amdgcn_mfma_f32_16x16x32_f16(af, bf1, acc[1], 0, 0, 0);
    };

    stage(0);
    commit(0);
    __syncthreads();
    for (int c = 1; c < 8; ++c) {
        stage(c * 32);
        compute((c - 1) & 1);
        commit(c & 1);
        __syncthreads();
    }
    compute(1);

#pragma unroll
    for (int r = 0; r < 4; ++r) {
        int gi = i0 + wy * 16 + lg * 4 + r;
        float ir = inv_rs[gi];
        out[(size_t)gi * DIM + d0 + wx * 32 + lm] = acc[0][r] * ir;
        out[(size_t)gi * DIM + d0 + wx * 32 + 16 + lm] = acc[1][r] * ir;
    }
}

// ---------------------------------------------------------------------------
extern "C" void kernel_launch(void* const* d_in, const int* in_sizes, int n_in,
                              void* d_out, int out_size, void* d_ws, size_t ws_size,
                              hipStream_t stream) {
    const float* T = (const float*)d_in[0];
    float* out = (float*)d_out;

    // workspace layout (16B-aligned, ~9.2 MB of 256 MiB):
    //   [0,        32768)    inv_norm  float[8192]
    //   [32768,    1081344)  s_part    double[512][256]
    //   [1081344,  1114112)  inv_rs    float[8192]
    //   [1114112,  1245184)  Mt        _Float16[256][256]  (M transposed)
    //   [1245184,  +8 MiB)   partials  float[32][256][256]
    char* ws = (char*)d_ws;
    float* inv_norm = (float*)(ws);
    double* s_part = (double*)(ws + 32768);
    float* inv_rs = (float*)(ws + 1081344);
    _Float16* Mt = (_Float16*)(ws + 1114112);
    float* partials = (float*)(ws + 1245184);

    k1_norm<<<512, 256, 0, stream>>>(T, inv_norm, s_part);
    k2_gemmM<<<576, 256, 0, stream>>>(T, inv_norm, s_part, inv_rs, partials);
    k_reduceM<<<256, 256, 0, stream>>>(partials, Mt);
    k3_mfma<<<1024, 256, 0, stream>>>(T, inv_norm, Mt, inv_rs, out);
}

// Round 10
// 95.122 us; speedup vs baseline: 3.1734x; 1.1767x over previous
//
#include <hip/hip_runtime.h>

#define N_ROWS 8192
#define DIM 256
#define EPSF 1e-8f

typedef _Float16 f16x8 __attribute__((ext_vector_type(8)));
typedef float f32x4 __attribute__((ext_vector_type(4)));

// ---------------------------------------------------------------------------
// D1: inv_norm (fp32) + fp64 column-sums of x_hat via LDS reduce + one
// f64 atomicAdd per thread (proven rounds 1-4).  512 blocks x 16 rows.
// ---------------------------------------------------------------------------
__global__ __launch_bounds__(256) void k1_norm(const float* __restrict__ T,
                                               float* __restrict__ inv_norm,
                                               double* __restrict__ s) {
    __shared__ double sacc[4][DIM];
    const int tid = threadIdx.x, bid = blockIdx.x;
    const int lane = tid & 63, wave = tid >> 6;
    double a0 = 0, a1 = 0, a2 = 0, a3 = 0;
#pragma unroll
    for (int r = 0; r < 4; ++r) {
        int row = bid * 16 + wave * 4 + r;
        float4 v = ((const float4*)(T + (size_t)row * DIM))[lane];
        float ss = v.x * v.x + v.y * v.y + v.z * v.z + v.w * v.w;
#pragma unroll
        for (int o = 32; o; o >>= 1) ss += __shfl_down(ss, o);
        ss = __shfl(ss, 0);
        float inv = 1.0f / fmaxf(sqrtf(ss), EPSF);
        if (lane == 0) inv_norm[row] = inv;
        a0 += (double)(v.x * inv);
        a1 += (double)(v.y * inv);
        a2 += (double)(v.z * inv);
        a3 += (double)(v.w * inv);
    }
    sacc[wave][lane * 4 + 0] = a0;
    sacc[wave][lane * 4 + 1] = a1;
    sacc[wave][lane * 4 + 2] = a2;
    sacc[wave][lane * 4 + 3] = a3;
    __syncthreads();
    double t = sacc[0][tid] + sacc[1][tid] + sacc[2][tid] + sacc[3][tid];
    atomicAdd(&s[tid], t);
}

// ---------------------------------------------------------------------------
// D2 (fused): blocks 0..511 = M-partials GEMM (fp16 MFMA, 64x64 tile,
// 256-row K-slab, double-buffered LDS, one barrier/chunk — r8-verified);
// blocks 512..2559 = inv_rs, ONE WAVE PER ROW (8192 independent waves;
// round-8's 44.7us straggler was 256 waves x 32 serial row-dots).
// Long-running gemm role first so it starts first; rs waves backfill.
// ---------------------------------------------------------------------------
__global__ __launch_bounds__(256) void k2_gemm_rs(const float* __restrict__ T,
                                                  const float* __restrict__ inv_norm,
                                                  const double* __restrict__ s,
                                                  float* __restrict__ inv_rs,
                                                  float* __restrict__ partials) {
    __shared__ _Float16 As[2][64][40];   // [buf][col][i]  10.2 KB
    __shared__ _Float16 Bs[2][64][40];   //                10.2 KB
    const int tid = threadIdx.x, bid = blockIdx.x;
    const int lane = tid & 63, wave = tid >> 6;

    if (bid >= 512) {
        // ---- rs role: row = one wave.  fp64 dot (precision-critical:
        // rs ~6e-4 possible from cancellation; abs err budget ~1e-5).
        const int row = (bid - 512) * 4 + wave;
        const double s0 = s[lane * 4 + 0];
        const double s1 = s[lane * 4 + 1];
        const double s2 = s[lane * 4 + 2];
        const double s3 = s[lane * 4 + 3];
        float4 v = ((const float4*)(T + (size_t)row * DIM))[lane];
        double d = (double)v.x * s0 + (double)v.y * s1 +
                   (double)v.z * s2 + (double)v.w * s3;
#pragma unroll
        for (int o = 32; o; o >>= 1) d += __shfl_down(d, o);
        if (lane == 0)
            inv_rs[row] = (float)(1.0 / (d * (double)inv_norm[row]));
        return;
    }

    // ---- gemm role: g in [0,512): (kx,dy,z) = (4,4,32)
    const int g = bid;
    const int k0 = (g & 3) * 64;
    const int d0 = ((g >> 2) & 3) * 64;
    const int i0 = (g >> 4) * 256;
    const int wy = wave >> 1, wx = wave & 1;      // 2x2 waves -> 32x32 each
    const int lm = lane & 15, lg = lane >> 4;
    const int i = tid & 31, c8 = (tid >> 5) * 8;  // stage map: row i, 8 cols
    f32x4 acc[2][2] = {};
    float4 rA[2], rB[2];
    float rI;

    auto stage = [&](int ic) {
        int gi = i0 + ic + i;
        rI = inv_norm[gi];
        const float* rowp = T + (size_t)gi * DIM;
        rA[0] = *(const float4*)(rowp + k0 + c8);
        rA[1] = *(const float4*)(rowp + k0 + c8 + 4);
        rB[0] = *(const float4*)(rowp + d0 + c8);
        rB[1] = *(const float4*)(rowp + d0 + c8 + 4);
    };
    auto commit = [&](int buf) {
#pragma unroll
        for (int j = 0; j < 2; ++j) {
            float4 a = rA[j], b = rB[j];
            int c = c8 + j * 4;
            As[buf][c + 0][i] = (_Float16)(a.x * rI);
            As[buf][c + 1][i] = (_Float16)(a.y * rI);
            As[buf][c + 2][i] = (_Float16)(a.z * rI);
            As[buf][c + 3][i] = (_Float16)(a.w * rI);
            Bs[buf][c + 0][i] = (_Float16)b.x;
            Bs[buf][c + 1][i] = (_Float16)b.y;
            Bs[buf][c + 2][i] = (_Float16)b.z;
            Bs[buf][c + 3][i] = (_Float16)b.w;
        }
    };
    auto compute = [&](int buf) {
        f16x8 af[2], bf[2];
#pragma unroll
        for (int mt = 0; mt < 2; ++mt)
            af[mt] = *(const f16x8*)&As[buf][wy * 32 + mt * 16 + lm][lg * 8];
#pragma unroll
        for (int nt = 0; nt < 2; ++nt)
            bf[nt] = *(const f16x8*)&Bs[buf][wx * 32 + nt * 16 + lm][lg * 8];
#pragma unroll
        for (int mt = 0; mt < 2; ++mt)
#pragma unroll
            for (int nt = 0; nt < 2; ++nt)
                acc[mt][nt] = __builtin_amdgcn_mfma_f32_16x16x32_f16(
                    af[mt], bf[nt], acc[mt][nt], 0, 0, 0);
    };

    stage(0);
    commit(0);
    __syncthreads();
    for (int c = 1; c < 8; ++c) {
        stage(c * 32);            // global loads for chunk c in flight
        compute((c - 1) & 1);     // MFMA on previous chunk
        commit(c & 1);            // write other buffer (no reader conflict)
        __syncthreads();          // ONE barrier per chunk
    }
    compute(1);

    // C/D frag: col = lane&15, row = (lane>>4)*4 + reg (mega-verified r5)
    float* pz = partials + (size_t)(g >> 4) * 65536;
#pragma unroll
    for (int mt = 0; mt < 2; ++mt) {
        int km = k0 + wy * 32 + mt * 16 + lg * 4;
#pragma unroll
        for (int nt = 0; nt < 2; ++nt) {
            int dn = d0 + wx * 32 + nt * 16 + lm;
#pragma unroll
            for (int r = 0; r < 4; ++r)
                pz[(size_t)(km + r) * 256 + dn] = acc[mt][nt][r];
        }
    }
}

// ---------------------------------------------------------------------------
// D3: reduce 32 partial slabs -> Mt (fp16, TRANSPOSED for k3's k-contiguous
// B loads).  Coalesced reads, 128 KB of writes.
// ---------------------------------------------------------------------------
__global__ __launch_bounds__(256) void k_reduceM(const float* __restrict__ partials,
                                                 _Float16* __restrict__ Mt) {
    const int gidx = blockIdx.x * 256 + threadIdx.x;
    const int k = gidx >> 8, d = gidx & 255;
    const float* p = partials + (size_t)k * 256 + d;
    float a0 = 0.f, a1 = 0.f, a2 = 0.f, a3 = 0.f;
#pragma unroll
    for (int z = 0; z < 32; z += 4) {
        a0 += p[(size_t)(z + 0) * 65536];
        a1 += p[(size_t)(z + 1) * 65536];
        a2 += p[(size_t)(z + 2) * 65536];
        a3 += p[(size_t)(z + 3) * 65536];
    }
    Mt[(size_t)d * 256 + k] = (_Float16)((a0 + a1) + (a2 + a3));
}

// ---------------------------------------------------------------------------
// D4: out = diag(inv_rs) * Xhat * M via fp16 MFMA.  32x64 tiles -> 1024
// blocks (4 blocks/CU), double-buffered LDS, one barrier per chunk.
// ---------------------------------------------------------------------------
__global__ __launch_bounds__(256) void k3_mfma(const float* __restrict__ T,
                                               const float* __restrict__ inv_norm,
                                               const _Float16* __restrict__ Mt,
                                               const float* __restrict__ inv_rs,
                                               float* __restrict__ out) {
    __shared__ _Float16 As[2][32][40];   // [buf][i][k]   5.1 KB
    __shared__ _Float16 Bs[2][64][40];   // [buf][d][k]  10.2 KB
    const int tid = threadIdx.x, bid = blockIdx.x;
    const int lane = tid & 63, wave = tid >> 6;
    const int i0 = (bid >> 2) * 32;
    const int d0 = (bid & 3) * 64;
    const int wy = wave >> 1, wx = wave & 1;     // wave tile 16 x 32
    const int lm = lane & 15, lg = lane >> 4;
    f32x4 acc[2] = {};
    float4 rA;
    float rI;
    f16x8 rB;
    const int ia = tid >> 3, c4 = (tid & 7) * 4;   // A: row ia, 4 k-cols
    const int db = tid >> 2, k8 = (tid & 3) * 8;   // B: row db, 8 k-cols

    auto stage = [&](int kc) {
        rI = inv_norm[i0 + ia];
        rA = *(const float4*)(T + (size_t)(i0 + ia) * DIM + kc + c4);
        rB = *(const f16x8*)(Mt + (size_t)(d0 + db) * 256 + kc + k8);
    };
    auto commit = [&](int buf) {
        As[buf][ia][c4 + 0] = (_Float16)(rA.x * rI);
        As[buf][ia][c4 + 1] = (_Float16)(rA.y * rI);
        As[buf][ia][c4 + 2] = (_Float16)(rA.z * rI);
        As[buf][ia][c4 + 3] = (_Float16)(rA.w * rI);
        *(f16x8*)&Bs[buf][db][k8] = rB;
    };
    auto compute = [&](int buf) {
        f16x8 af = *(const f16x8*)&As[buf][wy * 16 + lm][lg * 8];
        f16x8 bf0 = *(const f16x8*)&Bs[buf][wx * 32 + lm][lg * 8];
        f16x8 bf1 = *(const f16x8*)&Bs[buf][wx * 32 + 16 + lm][lg * 8];
        acc[0] = __builtin_amdgcn_mfma_f32_16x16x32_f16(af, bf0, acc[0], 0, 0, 0);
        acc[1] = __builtin_amdgcn_mfma_f32_16x16x32_f16(af, bf1, acc[1], 0, 0, 0);
    };

    stage(0);
    commit(0);
    __syncthreads();
    for (int c = 1; c < 8; ++c) {
        stage(c * 32);
        compute((c - 1) & 1);
        commit(c & 1);
        __syncthreads();
    }
    compute(1);

#pragma unroll
    for (int r = 0; r < 4; ++r) {
        int gi = i0 + wy * 16 + lg * 4 + r;
        float ir = inv_rs[gi];
        out[(size_t)gi * DIM + d0 + wx * 32 + lm] = acc[0][r] * ir;
        out[(size_t)gi * DIM + d0 + wx * 32 + 16 + lm] = acc[1][r] * ir;
    }
}

// ---------------------------------------------------------------------------
extern "C" void kernel_launch(void* const* d_in, const int* in_sizes, int n_in,
                              void* d_out, int out_size, void* d_ws, size_t ws_size,
                              hipStream_t stream) {
    const float* T = (const float*)d_in[0];
    float* out = (float*)d_out;

    // workspace layout (16B-aligned, ~8.5 MB of 256 MiB):
    //   [0,       32768)   inv_norm  float[8192]
    //   [32768,   34816)   s         double[256]
    //   [34816,   67584)   inv_rs    float[8192]
    //   [67584,   198656)  Mt        _Float16[256][256]  (M transposed)
    //   [198656,  +8 MiB)  partials  float[32][256][256]
    char* ws = (char*)d_ws;
    float* inv_norm = (float*)(ws);
    double* s = (double*)(ws + 32768);
    float* inv_rs = (float*)(ws + 34816);
    _Float16* Mt = (_Float16*)(ws + 67584);
    float* partials = (float*)(ws + 198656);

    hipMemsetAsync(s, 0, 256 * sizeof(double), stream);
    k1_norm<<<512, 256, 0, stream>>>(T, inv_norm, s);
    k2_gemm_rs<<<2560, 256, 0, stream>>>(T, inv_norm, s, inv_rs, partials);
    k_reduceM<<<256, 256, 0, stream>>>(partials, Mt);
    k3_mfma<<<1024, 256, 0, stream>>>(T, inv_norm, Mt, inv_rs, out);
}